// Round 8
// baseline (169.100 us; speedup 1.0000x reference)
//
#include <hip/hip_runtime.h>
#include <hip/hip_bf16.h>

// Problem: B=4096, L=50, D=64, E=128, CAT=384, U=256, V=100000
// Dtypes per reference: ALL float tensors fp32, ids/mask int32, out fp32 [B,E].
//
// Factored algebra: h = relu(q·W_q + k·W_k + (q*k)·W_qk + b_hide)
//   GEMM (swapped operands) C[u,l]: A-op = W fragments (global, coalesced),
//   B-op = [K | K*q] rows (LDS). C layout: col(lane&15)=l, row(quad*4+reg)=u.
//   qv[u] = b_hide[u] + q·W_q[:,u] via one N=16 MFMA tile per b (q planted in
//   the masked padding row 50 of that b's Kb half; garbage columns discarded).
// scores = (relu(C+qv)·W_out + b_out) * mask ; out[b] = scores · K   (fp32)
//
// History: V4 75.7 (W fragment coalescing, 2x). V5 112 REGRESSION (pipeline
// broke residency). V6 62.6 main but +22us prep -> total worse. V7 68.0 main,
// 156.3 total (qv folded into MFMA pipe). V7 accounting: every block reads all
// 192KB of g_W3 from L2 (no intra-block reuse, L1 too small) -> ~98MB/XCD ~=
// 23us, ~1/3 of main. V8: 2 b's per block (8 waves, wl=b half, N=128): W
// traffic and block count halve; per-wave work, acc (64), LDS layout per b,
// and ALL numerics bit-identical to V7. LDS 79.9KB -> exactly 2 blocks/CU =
// 16 waves/CU (same reg-capped residency as V7).

#define L_SEQ 50
#define LP    64
#define D_EMB 64
#define E_DIM 128
#define U_DIM 256
#define V_SZ  100000
#define B_TOT 4096
#define KSTR  136   // LDS row stride (bf16): 272B = 17*16B -> bank rotation by 4/row

typedef __bf16 bf16x2 __attribute__((ext_vector_type(2)));
typedef __bf16 bf16x4 __attribute__((ext_vector_type(4)));
typedef __bf16 bf16x8 __attribute__((ext_vector_type(8)));
typedef float  f32x4  __attribute__((ext_vector_type(4)));

// module-owned: g_W3 = ALL of W_hide in MFMA fragment order, 12 K-slices:
// g_W3[((s*16+ut)*64+lane)*8+j] = bf16(W_hide[(s*32 + (lane>>4)*8 + j)*256
//                                            + ut*16 + (lane&15)])
// s=0..3 -> W_q (c 0..127), s=4..7 -> W_k, s=8..11 -> W_qk.  192 KB.
__device__ __bf16 g_W3[12288 * 8];

// ---- prep: g_W3 fragment shuffle (48 blocks x 256 thr, one fragment/thread) ----
__global__ __launch_bounds__(256) void prep_kernel(const float* __restrict__ W_hide) {
  const int o = blockIdx.x * 256 + threadIdx.x;   // 0..12287
  const int s = o >> 10, ut = (o >> 6) & 15, lane = o & 63;
  const int quad = lane >> 4, m = lane & 15;
  const int u = ut * 16 + m;
  const int c0 = s * 32 + quad * 8;
  bf16x8 v;
#pragma unroll
  for (int j = 0; j < 8; ++j)
    v[j] = (__bf16)W_hide[(c0 + j) * 256 + u];  // scattered 4B reads (tiny kernel)
  *(bf16x8*)&g_W3[o * 8] = v;                   // coalesced 16B write
}

// ---- main: one block (8 waves, 512 threads) per 2 consecutive b ----
__global__ __launch_bounds__(512, 4) void din_main_kernel(
    const int* __restrict__ qid_item, const int* __restrict__ qid_cate,
    const int* __restrict__ seq_item, const int* __restrict__ seq_cate,
    const int* __restrict__ mask,
    const float* __restrict__ emb_item,
    const float* __restrict__ emb_cate,
    const float* __restrict__ b_hide,  // [256]
    const float* __restrict__ W_out,   // [256]
    const float* __restrict__ b_out,   // [1]
    float* __restrict__ out) {
  // KbA2: rows 0..127 = Kb (b0 rows 0..63, b1 rows 64..127), rows 128..255 = A2.
  // qv B-fragments read rows 50..65 (b0) / 114..129 (b1) — always in-bounds.
  __shared__ alignas(16) __bf16 KbA2[256 * KSTR];      // 69632 B
  __shared__ alignas(16) float qrowf[2][E_DIM];        // fp32 q per b
  __shared__ alignas(16) float qv_s[2][U_DIM];         // b_hide + q·W_q per b
  __shared__ float mask_f[2][LP];
  __shared__ float scpart[2][4][LP];                   // [b][wu][l]
  __shared__ float scores_s[2][LP];
  __shared__ float outp[2][4][E_DIM];                  // [b][wu][e]
  __bf16* const Kb = KbA2;                             // rows 0..127
  // A2 rows live at KbA2 + 128*KSTR

  const int b0 = blockIdx.x * 2;
  const int t = threadIdx.x;
  const int r = t >> 2, q4 = t & 3;      // r 0..127 spans both b's K rows
  const int rb = r >> 6, rloc = r & 63;  // which b, row within b
  const int col0 = q4 * 32;              // this thread's 32 cols of [item|cate]
  const int wave = t >> 6, lane = t & 63;
  const int wu = wave & 3, wl = wave >> 2;   // u-quarter, b-half
  const int m = lane & 15, quad = lane >> 4;

  // ---- phase 1: gather K rows (fp32) into regs, cast to LDS bf16 ----
  float4 kv[8];
  if (rloc < L_SEQ) {
    int id = (q4 < 2) ? seq_item[(b0 + rb) * L_SEQ + rloc]
                      : seq_cate[(b0 + rb) * L_SEQ + rloc];
    if ((unsigned)id >= (unsigned)V_SZ) id = 0;   // insurance
    const float4* s4 = (const float4*)(((q4 < 2) ? emb_item : emb_cate)
                                       + (size_t)id * D_EMB + (q4 & 1) * 32);
#pragma unroll
    for (int i = 0; i < 8; ++i) kv[i] = s4[i];
  } else {
#pragma unroll
    for (int i = 0; i < 8; ++i) kv[i] = make_float4(0.f, 0.f, 0.f, 0.f);
  }
#pragma unroll
  for (int i = 0; i < 8; ++i) {
    bf16x4 h4 = {(__bf16)kv[i].x, (__bf16)kv[i].y, (__bf16)kv[i].z, (__bf16)kv[i].w};
    *(bf16x4*)&Kb[r * KSTR + col0 + i * 4] = h4;   // 8B store, aligned
  }
  if (t < 8) {   // q rows: 8 threads x 32 floats (2 b's)
    const int bb = t >> 2, tt = t & 3;
    int id = (tt < 2) ? qid_item[b0 + bb] : qid_cate[b0 + bb];
    if ((unsigned)id >= (unsigned)V_SZ) id = 0;
    const float4* s4 = (const float4*)(((tt < 2) ? emb_item : emb_cate)
                                       + (size_t)id * D_EMB + (tt & 1) * 32);
    float4* d4 = (float4*)&qrowf[bb][tt * 32];
#pragma unroll
    for (int i = 0; i < 8; ++i) d4[i] = s4[i];
  }
  if (t < 128) {
    const int bb = t >> 6, l = t & 63;
    mask_f[bb][l] = (l < L_SEQ && mask[(b0 + bb) * L_SEQ + l] != 0) ? 1.0f : 0.0f;
  }
  __syncthreads();

  // ---- phase 2: A2 = bf16(K * q) from fp32 regs (single rounding);
  //      plant bf16(q_b) into each b's masked padding row 50 (rows 50 / 114) ----
#pragma unroll
  for (int i = 0; i < 8; ++i) {
    const float* qp = &qrowf[rb][col0 + i * 4];
    bf16x4 h4 = {(__bf16)(kv[i].x * qp[0]), (__bf16)(kv[i].y * qp[1]),
                 (__bf16)(kv[i].z * qp[2]), (__bf16)(kv[i].w * qp[3])};
    *(bf16x4*)&KbA2[(128 + r) * KSTR + col0 + i * 4] = h4;
  }
  if (rloc == 50) {
#pragma unroll
    for (int i = 0; i < 8; ++i) {
      const float* qp = &qrowf[rb][col0 + i * 4];
      bf16x4 h4 = {(__bf16)qp[0], (__bf16)qp[1], (__bf16)qp[2], (__bf16)qp[3]};
      *(bf16x4*)&Kb[r * KSTR + col0 + i * 4] = h4;
    }
  }
  __syncthreads();

  // ---- phase 3a: qv via MFMA, one N=16 tile per b (wl picks b).
  //      B rows = (50 + 64*wl + m): row 50/114 = q_b, rest garbage (discarded).
  {
    f32x4 acc2[4];
#pragma unroll
    for (int mt = 0; mt < 4; ++mt) acc2[mt] = (f32x4){0.f, 0.f, 0.f, 0.f};
#pragma unroll
    for (int s = 0; s < 4; ++s) {
      const int klocal = s * 32 + quad * 8;
      bf16x8 kq = *(const bf16x8*)&KbA2[(50 + 64 * wl + m) * KSTR + klocal];
      bf16x8 wq[4];
#pragma unroll
      for (int mt = 0; mt < 4; ++mt)
        wq[mt] = *(const bf16x8*)&g_W3[(s * 1024 + (wu * 4 + mt) * 64 + lane) * 8];
#pragma unroll
      for (int mt = 0; mt < 4; ++mt)
        acc2[mt] = __builtin_amdgcn_mfma_f32_16x16x32_bf16(wq[mt], kq, acc2[mt],
                                                           0, 0, 0);
    }
    if (m == 0) {   // only column 0 (B-row = q_b) is the true qv
#pragma unroll
      for (int mt = 0; mt < 4; ++mt) {
        const int u0 = wu * 64 + mt * 16 + quad * 4;
        float4 bh = *(const float4*)&b_hide[u0];
        f32x4 v = acc2[mt];
        v[0] += bh.x; v[1] += bh.y; v[2] += bh.z; v[3] += bh.w;
        *(f32x4*)&qv_s[wl][u0] = v;
      }
    }
  }
  __syncthreads();   // qv_s visible to all epilogue readers

  // ---- phase 3b: main MFMA. M=u (64/wave on wu), N=l (64 of this wave's b),
  //      K=256 (slices 4..11). A-op = g_W3 fragments, B-op = Kb/A2 half (LDS).
  f32x4 acc[4][4];
#pragma unroll
  for (int mt = 0; mt < 4; ++mt)
#pragma unroll
    for (int nt = 0; nt < 4; ++nt) acc[mt][nt] = (f32x4){0.f, 0.f, 0.f, 0.f};

#pragma unroll
  for (int s = 0; s < 8; ++s) {
    const int base_row = ((s < 4) ? 0 : 128) + 64 * wl;
    const int klocal = (s & 3) * 32 + quad * 8;
    bf16x8 wfr[4], kfr[4];
#pragma unroll
    for (int mt = 0; mt < 4; ++mt) {
      const int o = (4 + s) * 1024 + (wu * 4 + mt) * 64 + lane;  // frag-ordered
      wfr[mt] = *(const bf16x8*)&g_W3[o * 8];
    }
#pragma unroll
    for (int nt = 0; nt < 4; ++nt)
      kfr[nt] = *(const bf16x8*)&KbA2[(base_row + nt * 16 + m) * KSTR + klocal];
#pragma unroll
    for (int mt = 0; mt < 4; ++mt)
#pragma unroll
      for (int nt = 0; nt < 4; ++nt)
        acc[mt][nt] = __builtin_amdgcn_mfma_f32_16x16x32_bf16(
            wfr[mt], kfr[nt], acc[mt][nt], 0, 0, 0);
  }
  // no barrier needed: epilogue reads private acc + qv_s (sync'd above) + W_out

  // ---- epilogue: C[u,l]: u = wu*64+mt*16+quad*4+rg (in-lane), l = nt*16+m.
  //      part[nt] = sum_u relu(C+qv[u])*W_out[u]  — u-reduce in-lane + quads.
  float qv4[4][4], wo4[4][4];
#pragma unroll
  for (int mt = 0; mt < 4; ++mt) {
    const int u0 = wu * 64 + mt * 16 + quad * 4;
    f32x4 qq = *(const f32x4*)&qv_s[wl][u0];    // LDS broadcast per 16 lanes
    float4 ww = *(const float4*)&W_out[u0];
    qv4[mt][0] = qq[0]; qv4[mt][1] = qq[1]; qv4[mt][2] = qq[2]; qv4[mt][3] = qq[3];
    wo4[mt][0] = ww.x;  wo4[mt][1] = ww.y;  wo4[mt][2] = ww.z;  wo4[mt][3] = ww.w;
  }
  float part[4];
#pragma unroll
  for (int nt = 0; nt < 4; ++nt) {
    float sum = 0.f;
#pragma unroll
    for (int mt = 0; mt < 4; ++mt)
#pragma unroll
      for (int rg = 0; rg < 4; ++rg) {
        float h = acc[mt][nt][rg] + qv4[mt][rg];
        h = fmaxf(h, 0.f);
        sum += h * wo4[mt][rg];
      }
    part[nt] = sum;
  }
#pragma unroll
  for (int nt = 0; nt < 4; ++nt) {   // reduce over 4 quads
    part[nt] += __shfl_xor(part[nt], 16, 64);
    part[nt] += __shfl_xor(part[nt], 32, 64);
  }
  if (lane < 16) {
#pragma unroll
    for (int nt = 0; nt < 4; ++nt)
      scpart[wl][wu][nt * 16 + lane] = part[nt];   // l = nt*16+lane
  }
  __syncthreads();

  // ---- scores (t<128: both b's), then wave-parallel out partials ----
  if (t < 128) {
    const int bb = t >> 6, l = t & 63;
    float s = scpart[bb][0][l] + scpart[bb][1][l] + scpart[bb][2][l]
            + scpart[bb][3][l] + b_out[0];
    scores_s[bb][l] = s * mask_f[bb][l];
  }
  __syncthreads();
  // wave (wu,wl) accumulates its b's K rows [wu*16, wu*16+16);
  // lane covers e = 2*lane, 2*lane+1
  {
    const int e2 = lane * 2;
    float o0 = 0.f, o1 = 0.f;
#pragma unroll
    for (int i2 = 0; i2 < 16; ++i2) {
      const int l = wu * 16 + i2;
      const float sc = scores_s[wl][l];                            // broadcast
      bf16x2 kk = *(const bf16x2*)&Kb[(64 * wl + l) * KSTR + e2];  // b32 pair
      o0 += sc * (float)kk[0];
      o1 += sc * (float)kk[1];
    }
    outp[wl][wu][e2]     = o0;
    outp[wl][wu][e2 + 1] = o1;
  }
  __syncthreads();
  if (t < 256) {
    const int bb = t >> 7, e = t & 127;
    float o = outp[bb][0][e] + outp[bb][1][e] + outp[bb][2][e] + outp[bb][3][e];
    out[(size_t)(b0 + bb) * E_DIM + e] = o;
  }
}

extern "C" void kernel_launch(void* const* d_in, const int* in_sizes, int n_in,
                              void* d_out, int out_size, void* d_ws, size_t ws_size,
                              hipStream_t stream) {
  const int* qid_item = (const int*)d_in[0];
  const int* qid_cate = (const int*)d_in[1];
  const int* seq_item = (const int*)d_in[2];
  const int* seq_cate = (const int*)d_in[3];
  const int* mask     = (const int*)d_in[4];
  const float* emb_item = (const float*)d_in[5];
  const float* emb_cate = (const float*)d_in[6];
  const float* W_hide   = (const float*)d_in[7];
  const float* b_hide   = (const float*)d_in[8];
  const float* W_out    = (const float*)d_in[9];
  const float* b_out    = (const float*)d_in[10];
  float* out = (float*)d_out;

  (void)d_ws; (void)ws_size;  // intentionally unused

  prep_kernel<<<48, 256, 0, stream>>>(W_hide);
  din_main_kernel<<<B_TOT / 2, 512, 0, stream>>>(qid_item, qid_cate, seq_item,
                                                 seq_cate, mask, emb_item, emb_cate,
                                                 b_hide, W_out, b_out, out);
}